// Round 1
// baseline (82.765 us; speedup 1.0000x reference)
//
#include <hip/hip_runtime.h>
#include <cstdint>

// ---------------------------------------------------------------------------
// FP8 QDQ Conv2d:  out = conv2d(qdq_fp8(x,2), w*2, pad=1) + bias
//                = 4 * conv2d(fp8(x/2), fp8(w)) + bias     (exact in fp8)
// x: (32,128,56,56) f32 NCHW; w: (256,128,3,3) f32 (fp8-representable); b: (256,)
// out: (32,256,56,56) f32.
// Implicit GEMM: M = 32*56*56 = 100352 (= 784*128), N = 256, K = 9*128.
// ---------------------------------------------------------------------------

#define NB   32
#define CIN  128
#define HW   56
#define KOUT 256

#define ACT_BYTES (32u * 56u * 56u * 128u)      // 12,845,056  NHWC fp8
#define WT_OFF    ACT_BYTES
#define WT_BYTES  (9u * 256u * 128u)            // 294,912     [rs][k][c] fp8
#define ZP_OFF    (WT_OFF + WT_BYTES)           // 128B zero page for halo rows

typedef float        f32x4 __attribute__((ext_vector_type(4)));
typedef unsigned int u32x4 __attribute__((ext_vector_type(4)));

// --------------------------- fp8 pack helpers ------------------------------
__device__ __forceinline__ unsigned int pack2_fp8(float a, float b) {
  a = fminf(fmaxf(a, -448.f), 448.f);
  b = fminf(fmaxf(b, -448.f), 448.f);
  // v_cvt_pk_fp8_f32: RNE, saturating, OCP e4m3fn on gfx950. byte0=a, byte1=b.
  return (unsigned int)__builtin_amdgcn_cvt_pk_fp8_f32(a, b, 0, false);
}

// ------------------- kernel 1: qdq + NCHW -> NHWC fp8 ----------------------
// One block per (n,h) row: reads 128c x 56w f32 (coalesced along w per c-slice),
// writes 56*128 = 7168 fp8 bytes.
__global__ __launch_bounds__(256) void qdq_pack(const float* __restrict__ X,
                                                unsigned char* __restrict__ act) {
  const int nh = blockIdx.x;               // 0..1791
  const int n = nh / HW, h = nh - n * HW;
  const float* xb = X + (size_t)n * (CIN * HW * HW) + h * HW;  // + c*3136 + w
  unsigned char* ob = act + (size_t)nh * (HW * CIN);

  for (int i = 0; i < 2; ++i) {
    int item = threadIdx.x + i * 256;
    if (item >= HW * 8) break;             // 56 w * 8 c-groups of 16
    int w = item % HW, cg = item / HW;
    unsigned int dw[4];
#pragma unroll
    for (int jj = 0; jj < 4; ++jj) {
      int c0 = cg * 16 + jj * 4;
      float v0 = xb[(c0 + 0) * 3136 + w] * 0.5f;
      float v1 = xb[(c0 + 1) * 3136 + w] * 0.5f;
      float v2 = xb[(c0 + 2) * 3136 + w] * 0.5f;
      float v3 = xb[(c0 + 3) * 3136 + w] * 0.5f;
      unsigned int lo = pack2_fp8(v0, v1) & 0xffffu;
      unsigned int hi = pack2_fp8(v2, v3) & 0xffffu;
      dw[jj] = lo | (hi << 16);
    }
    u32x4 v = {dw[0], dw[1], dw[2], dw[3]};
    *(u32x4*)(ob + w * CIN + cg * 16) = v;
  }
}

// --------------- kernel 2: weight OIHW f32 -> [rs][k][c] fp8 ---------------
// Also zeroes the 128B halo zero-page (block 0). Coalesced dword writes.
__global__ __launch_bounds__(256) void pack_weight(const float* __restrict__ W,
                                                   unsigned char* __restrict__ wt,
                                                   unsigned int* __restrict__ zp) {
  if (blockIdx.x == 0 && threadIdx.x < 32) zp[threadIdx.x] = 0u;
  int gid = blockIdx.x * 256 + threadIdx.x;   // one dword (4 c) per thread
  int o = gid * 4;
  if (o >= (int)WT_BYTES) return;
  int rs = o >> 15;                // /32768 (= 256*128)
  int rem = o & 32767;
  int k  = rem >> 7;
  int c0 = rem & 127;
  // W[k][c][r][s] at k*1152 + c*9 + rs
  float v0 = W[k * 1152 + (c0 + 0) * 9 + rs];
  float v1 = W[k * 1152 + (c0 + 1) * 9 + rs];
  float v2 = W[k * 1152 + (c0 + 2) * 9 + rs];
  float v3 = W[k * 1152 + (c0 + 3) * 9 + rs];
  unsigned int dw = (pack2_fp8(v0, v1) & 0xffffu) | (pack2_fp8(v2, v3) << 16);
  *(unsigned int*)(wt + o) = dw;
}

// ------------------------- kernel 3: implicit GEMM -------------------------
__device__ __forceinline__ void g2l16(const void* g, void* l) {
  __builtin_amdgcn_global_load_lds((const __attribute__((address_space(1))) void*)g,
                                   (__attribute__((address_space(3))) void*)l,
                                   16, 0, 0);
}

__global__ __launch_bounds__(256) void conv_mfma(const unsigned char* __restrict__ act,
                                                 const unsigned char* __restrict__ wt,
                                                 const unsigned char* __restrict__ zp,
                                                 const float* __restrict__ bias,
                                                 float* __restrict__ out) {
  __shared__ __align__(16) unsigned char lds[32768];  // A:[0,16K) [m][c], B:[16K,32K) [k][c]
  const int tid  = threadIdx.x;
  const int lane = tid & 63;
  const int wid  = tid >> 6;
  const int wr   = wid >> 1, wc = wid & 1;            // 2x2 waves -> 64x64 each
  const int bm   = blockIdx.x << 7;                   // 784 m-tiles
  const int bn   = blockIdx.y << 7;                   // 2 k-tiles

  // staging geometry: 8 threads x 16B per 128B row; 32 rows/round, 4 rounds
  const int srow   = tid >> 3;                        // 0..31
  const int sphys  = (tid & 7) << 4;                  // linear LDS dest chunk
  const int schunk = ((tid & 7) ^ (srow & 7)) << 4;   // XOR-swizzled global src chunk

  int an_[4], ah_[4], aw_[4];
#pragma unroll
  for (int q = 0; q < 4; ++q) {
    int m = bm + srow + 32 * q;
    int n = m / 3136;
    int hw = m - n * 3136;
    int h = hw / 56;
    an_[q] = n; ah_[q] = h; aw_[q] = hw - h * 56;
  }

  const f32x4 zero = {0.f, 0.f, 0.f, 0.f};
  f32x4 acc[4][4];
#pragma unroll
  for (int i = 0; i < 4; ++i)
#pragma unroll
    for (int j = 0; j < 4; ++j) acc[i][j] = zero;

  for (int rs = 0; rs < 9; ++rs) {
    const int r = rs / 3, s = rs - 3 * (rs / 3);
    const unsigned char* wseg = wt + rs * (KOUT * CIN);

    // stage A tile: 128 rows x 128B (halo rows -> zero page)
#pragma unroll
    for (int q = 0; q < 4; ++q) {
      int hi = ah_[q] + r - 1;
      int wi = aw_[q] + s - 1;
      bool ok = ((unsigned)hi < 56u) && ((unsigned)wi < 56u);
      const unsigned char* src =
          ok ? act + (((an_[q] * 56 + hi) * 56 + wi) << 7) + schunk : zp + schunk;
      g2l16(src, &lds[((srow + 32 * q) << 7) + sphys]);
    }
    // stage B tile: 128 k-rows x 128B of c
#pragma unroll
    for (int q = 0; q < 4; ++q) {
      int kl = srow + 32 * q;
      g2l16(wseg + ((bn + kl) << 7) + schunk, &lds[16384 + (kl << 7) + sphys]);
    }
    __syncthreads();

    const int kgrp = (lane >> 4) << 3;       // 8 k-bytes per lane-group
    const int xa   = (lane & 7) << 4;        // read-side swizzle (row&7 == lane&7)
#pragma unroll
    for (int kk = 0; kk < 4; ++kk) {
      const int kb = kk * 32 + kgrp;
      long av[4], bv[4];
#pragma unroll
      for (int mi = 0; mi < 4; ++mi) {
        int row = (wr << 6) + (mi << 4) + (lane & 15);
        av[mi] = *(const long*)(&lds[(row << 7) + (kb ^ xa)]);
      }
#pragma unroll
      for (int ni = 0; ni < 4; ++ni) {
        int col = (wc << 6) + (ni << 4) + (lane & 15);
        bv[ni] = *(const long*)(&lds[16384 + (col << 7) + (kb ^ xa)]);
      }
#pragma unroll
      for (int mi = 0; mi < 4; ++mi)
#pragma unroll
        for (int ni = 0; ni < 4; ++ni)
          acc[mi][ni] = __builtin_amdgcn_mfma_f32_16x16x32_fp8_fp8(
              av[mi], bv[ni], acc[mi][ni], 0, 0, 0);
    }
    __syncthreads();
  }

  // epilogue: out[n][k][hw] = 4*acc + bias[k]; 4 consecutive m per lane = float4
#pragma unroll
  for (int ni = 0; ni < 4; ++ni) {
    int k = bn + (wc << 6) + (ni << 4) + (lane & 15);
    float bvv = bias[k];
#pragma unroll
    for (int mi = 0; mi < 4; ++mi) {
      int m = bm + (wr << 6) + (mi << 4) + ((lane >> 4) << 2);
      int n = m / 3136;
      int hw = m - n * 3136;
      f32x4 v = acc[mi][ni];
      v = v * 4.0f + bvv;
      *(f32x4*)(out + (size_t)(n * KOUT + k) * 3136 + hw) = v;
    }
  }
}

// ---------------------------------------------------------------------------
extern "C" void kernel_launch(void* const* d_in, const int* in_sizes, int n_in,
                              void* d_out, int out_size, void* d_ws, size_t ws_size,
                              hipStream_t stream) {
  const float* X = (const float*)d_in[0];
  const float* W = (const float*)d_in[1];
  const float* B = (const float*)d_in[2];
  float* out = (float*)d_out;

  unsigned char* act = (unsigned char*)d_ws;
  unsigned char* wtb = act + WT_OFF;
  unsigned char* zp  = act + ZP_OFF;

  hipLaunchKernelGGL(qdq_pack,    dim3(NB * HW), dim3(256), 0, stream, X, act);
  hipLaunchKernelGGL(pack_weight, dim3(288),     dim3(256), 0, stream, W, wtb,
                     (unsigned int*)zp);
  hipLaunchKernelGGL(conv_mfma,   dim3(784, 2),  dim3(256), 0, stream, act, wtb, zp, B,
                     out);
}